// Round 3
// baseline (2712.500 us; speedup 1.0000x reference)
//
#include <hip/hip_runtime.h>
#include <math.h>

#define TOKS (128*199)   // 25472
#define DM 128
#define DI 256
#define DS 16
#define DR 8
#define NBLK 4
#define LSEQ 199
#define BATCH 128

__device__ __forceinline__ float gelu_f(float x) {
  return 0.5f * x * (1.0f + erff(x * 0.70710678118654752440f));
}
__device__ __forceinline__ float silu_f(float x) {
  return x / (1.0f + expf(-x));
}

// ---------------- Stem: conv1d stride 5, kernel 10, 12 leads -> 128 ch ----------------
__global__ void pe_conv_kernel(const float* __restrict__ x, const float* __restrict__ pw,
                               const float* __restrict__ pb, float* __restrict__ convo) {
  int b = blockIdx.x;
  __shared__ float sx[12000];
  for (int i = threadIdx.x; i < 12000; i += 256) sx[i] = x[(size_t)b*12000 + i];
  __syncthreads();
  for (int o = threadIdx.x; o < DM*LSEQ; o += 256) {
    int m = o / LSEQ, t = o - m*LSEQ;
    const float* wr = pw + m*120;
    const float* xt = sx + t*5;
    float acc = pb[m];
#pragma unroll
    for (int l = 0; l < 12; ++l) {
#pragma unroll
      for (int k = 0; k < 10; ++k)
        acc += xt[l*1000 + k] * wr[l*10 + k];
    }
    convo[((size_t)b*DM + m)*LSEQ + t] = acc;
  }
}

// ---------------- GroupNorm(8 groups) + GELU + transpose + pos add ----------------
__global__ void gn_kernel(const float* __restrict__ conv, const float* __restrict__ gg,
                          const float* __restrict__ gb, const float* __restrict__ pos,
                          float* __restrict__ h) {
  int b = blockIdx.x >> 3, grp = blockIdx.x & 7;
  const float* cb = conv + ((size_t)b*DM + grp*16)*LSEQ;
  int tid = threadIdx.x;
  float s = 0.f, s2 = 0.f;
  for (int i = tid; i < 16*LSEQ; i += 256) { float v = cb[i]; s += v; s2 += v*v; }
#pragma unroll
  for (int m = 1; m < 64; m <<= 1) { s += __shfl_xor(s, m); s2 += __shfl_xor(s2, m); }
  __shared__ float red[8];
  int lane = tid & 63, wid = tid >> 6;
  if (lane == 0) { red[wid] = s; red[4+wid] = s2; }
  __syncthreads();
  float S  = red[0]+red[1]+red[2]+red[3];
  float S2 = red[4]+red[5]+red[6]+red[7];
  const float inv = 1.0f/(16.0f*LSEQ);
  float mean = S*inv;
  float var  = S2*inv - mean*mean;
  float rstd = rsqrtf(var + 1e-5f);
  for (int i = tid; i < 16*LSEQ; i += 256) {
    int mloc = i / LSEQ; int t = i - mloc*LSEQ;
    int m = grp*16 + mloc;
    float v = (cb[i] - mean)*rstd*gg[m] + gb[m];
    v = gelu_f(v);
    h[((size_t)b*LSEQ + t)*DM + m] = v + pos[t*DM + m];
  }
}

// ---------------- LayerNorm over DM=128, one wave per token ----------------
__global__ void ln_kernel(const float* __restrict__ x, const float* __restrict__ g,
                          const float* __restrict__ bb, float* __restrict__ o) {
  int tok = blockIdx.x*4 + (threadIdx.x >> 6);
  int lane = threadIdx.x & 63;
  const float* xr = x + (size_t)tok*DM;
  float v0 = xr[lane], v1 = xr[lane+64];
  float s = v0+v1, s2 = v0*v0+v1*v1;
#pragma unroll
  for (int m=1;m<64;m<<=1){ s += __shfl_xor(s,m); s2 += __shfl_xor(s2,m); }
  float mean = s*(1.f/DM);
  float var  = s2*(1.f/DM) - mean*mean;
  float rs = rsqrtf(var+1e-5f);
  float* orow = o + (size_t)tok*DM;
  orow[lane]    = (v0-mean)*rs*g[lane]+bb[lane];
  orow[lane+64] = (v1-mean)*rs*g[lane+64]+bb[lane+64];
}

// ---------------- Generic tiled fp32 GEMM: C[M,N] = act(A[M,K] @ W[N,K]^T + bias) (+C) --
template<int ACT, int RESID, int BIAS>
__global__ __launch_bounds__(256) void gemm_kernel(
    const float* __restrict__ A, const float* __restrict__ W,
    const float* __restrict__ bias, float* __restrict__ C,
    int N, int K) {
  __shared__ float As[64][17];
  __shared__ float Ws[64][17];
  int tid = threadIdx.x;
  int tx = tid & 15, ty = tid >> 4;
  const float* Ab = A + (size_t)blockIdx.x*64*K;
  const float* Wb = W + (size_t)blockIdx.y*64*K;
  float acc[4][4] = {};
  int r = tid >> 2, c4 = (tid & 3) << 2;
  for (int k0 = 0; k0 < K; k0 += 16) {
    float4 av = *(const float4*)(Ab + (size_t)r*K + k0 + c4);
    float4 wv = *(const float4*)(Wb + (size_t)r*K + k0 + c4);
    As[r][c4]=av.x; As[r][c4+1]=av.y; As[r][c4+2]=av.z; As[r][c4+3]=av.w;
    Ws[r][c4]=wv.x; Ws[r][c4+1]=wv.y; Ws[r][c4+2]=wv.z; Ws[r][c4+3]=wv.w;
    __syncthreads();
#pragma unroll
    for (int k=0;k<16;k++) {
      float a0=As[ty*4+0][k], a1=As[ty*4+1][k], a2=As[ty*4+2][k], a3=As[ty*4+3][k];
      float w0=Ws[tx*4+0][k], w1=Ws[tx*4+1][k], w2=Ws[tx*4+2][k], w3=Ws[tx*4+3][k];
      acc[0][0]+=a0*w0; acc[0][1]+=a0*w1; acc[0][2]+=a0*w2; acc[0][3]+=a0*w3;
      acc[1][0]+=a1*w0; acc[1][1]+=a1*w1; acc[1][2]+=a1*w2; acc[1][3]+=a1*w3;
      acc[2][0]+=a2*w0; acc[2][1]+=a2*w1; acc[2][2]+=a2*w2; acc[2][3]+=a2*w3;
      acc[3][0]+=a3*w0; acc[3][1]+=a3*w1; acc[3][2]+=a3*w2; acc[3][3]+=a3*w3;
    }
    __syncthreads();
  }
  int row0 = blockIdx.x*64 + ty*4;
  int col0 = blockIdx.y*64 + tx*4;
#pragma unroll
  for (int i=0;i<4;i++) {
    float* cp = C + (size_t)(row0+i)*N + col0;
#pragma unroll
    for (int j=0;j<4;j++) {
      float v = acc[i][j];
      if (BIAS) v += bias[col0+j];
      if (ACT)  v = gelu_f(v);
      if (RESID) v += cp[j];
      cp[j] = v;
    }
  }
}

// ---------------- Depthwise causal conv (k=4) + bias + SiLU ----------------
__global__ void dwconv_kernel(const float* __restrict__ xz, const float* __restrict__ w,
                              const float* __restrict__ bias, float* __restrict__ uss) {
  int tok = blockIdx.x;
  int d = threadIdx.x;
  int b = tok / LSEQ, t = tok - b*LSEQ;
  float4 wv = *(const float4*)(w + d*4);
  float acc = bias[d];
  const float* xp = xz + ((size_t)b*LSEQ)*512 + d;
  if (t >= 3) acc += xp[(size_t)(t-3)*512]*wv.x;
  if (t >= 2) acc += xp[(size_t)(t-2)*512]*wv.y;
  if (t >= 1) acc += xp[(size_t)(t-1)*512]*wv.z;
  acc += xp[(size_t)t*512]*wv.w;
  uss[(size_t)tok*DI + d] = silu_f(acc);
}

// ---------------- xproj (256->40) + dtproj (8->256) + softplus, fused ----------------
__global__ __launch_bounds__(256) void xproj_kernel(
    const float* __restrict__ uss, const float* __restrict__ xw,
    const float* __restrict__ dtw, const float* __restrict__ dtb,
    float* __restrict__ dlt, float* __restrict__ Bmw, float* __restrict__ Cmw) {
  __shared__ float su[64*257];
  __shared__ float sdbl[64*40];
  int tok0 = blockIdx.x * 64;
  int tid = threadIdx.x;
  const float4* gsrc = (const float4*)(uss + (size_t)tok0*DI);
  for (int i4 = tid; i4 < 64*64; i4 += 256) {
    float4 v = gsrc[i4];
    int tt = i4 >> 6, k4 = (i4 & 63) << 2;
    float* dst = su + tt*257 + k4;
    dst[0]=v.x; dst[1]=v.y; dst[2]=v.z; dst[3]=v.w;
  }
  __syncthreads();
  for (int o = tid; o < 64*40; o += 256) {
    int j = o >> 6, tt = o & 63;
    const float* wr = xw + j*DI;
    const float* ur = su + tt*257;
    float acc = 0.f;
#pragma unroll 8
    for (int k=0;k<DI;k++) acc += ur[k]*wr[k];
    sdbl[tt*40 + j] = acc;
  }
  __syncthreads();
  for (int o = tid; o < 64*DI; o += 256) {
    int tt = o >> 8, d = o & 255;
    const float* dr = sdbl + tt*40;
    float acc = dtb[d];
#pragma unroll
    for (int r=0;r<DR;r++) acc += dr[r]*dtw[d*DR+r];
    acc = (acc > 20.f) ? acc : log1pf(expf(acc));
    dlt[((size_t)tok0+tt)*DI + d] = acc;
  }
  for (int o = tid; o < 64*32; o += 256) {
    int tt = o >> 5, s = o & 31;
    float v = sdbl[tt*40 + 8 + s];
    if (s < 16) Bmw[((size_t)tok0+tt)*DS + s] = v;
    else        Cmw[((size_t)tok0+tt)*DS + (s-16)] = v;
  }
}

// ---------------- Selective scan; y written in-place over delta; gated by silu(z) ------
// One block per batch element: 256 threads = 4 waves cover all DI=256 channels;
// B/C staged once per b.
__global__ __launch_bounds__(256) void scan_kernel(
    const float* __restrict__ uss, float* __restrict__ dlt_y,
    const float* __restrict__ Bmw, const float* __restrict__ Cmw,
    const float* __restrict__ A_log, const float* __restrict__ Dp,
    const float* __restrict__ xz) {
  int b = blockIdx.x;
  int d = threadIdx.x;
  __shared__ float sB[LSEQ*DS], sC[LSEQ*DS];
  for (int i = threadIdx.x; i < LSEQ*DS; i += 256) {
    sB[i] = Bmw[(size_t)b*LSEQ*DS + i];
    sC[i] = Cmw[(size_t)b*LSEQ*DS + i];
  }
  __syncthreads();
  float A[DS];
#pragma unroll
  for (int s=0;s<DS;s++) A[s] = -expf(A_log[d*DS+s]);
  float Dd = Dp[d];
  float hs[DS];
#pragma unroll
  for (int s=0;s<DS;s++) hs[s]=0.f;
  const size_t base0 = (size_t)b*LSEQ;
  for (int t=0;t<LSEQ;t++) {
    size_t tb = base0 + t;
    float dt = dlt_y[tb*DI + d];
    float u  = uss[tb*DI + d];
    float z  = xz[tb*512 + 256 + d];
    float du = dt*u;
    float yv = 0.f;
#pragma unroll
    for (int s=0;s<DS;s++) {
      float dA = expf(dt*A[s]);
      hs[s] = dA*hs[s] + du*sB[t*DS+s];
      yv += hs[s]*sC[t*DS+s];
    }
    yv = (yv + u*Dd) * silu_f(z);
    dlt_y[tb*DI + d] = yv;
  }
}

// ---------------- Final: LN + mean over t + head GEMM + GELU ----------------
__global__ void final_kernel(const float* __restrict__ h, const float* __restrict__ g,
                             const float* __restrict__ bta, const float* __restrict__ hw,
                             const float* __restrict__ hb, float* __restrict__ out) {
  int b = blockIdx.x;
  int tid = threadIdx.x, lane = tid & 63, wid = tid >> 6;
  float s0 = 0.f, s1 = 0.f;
  for (int t = wid; t < LSEQ; t += 4) {
    const float* hr = h + ((size_t)b*LSEQ + t)*DM;
    float v0 = hr[lane], v1 = hr[lane+64];
    float ss = v0+v1, ss2 = v0*v0+v1*v1;
#pragma unroll
    for (int m=1;m<64;m<<=1){ ss += __shfl_xor(ss,m); ss2 += __shfl_xor(ss2,m); }
    float mean = ss*(1.f/DM);
    float var  = ss2*(1.f/DM)-mean*mean;
    float rs = rsqrtf(var+1e-5f);
    s0 += (v0-mean)*rs*g[lane]+bta[lane];
    s1 += (v1-mean)*rs*g[lane+64]+bta[lane+64];
  }
  __shared__ float sm[4][128];
  sm[wid][lane] = s0; sm[wid][lane+64] = s1;
  __syncthreads();
  __shared__ float mv[128];
  if (tid < 128) mv[tid] = (sm[0][tid]+sm[1][tid]+sm[2][tid]+sm[3][tid]) * (1.f/199.f);
  __syncthreads();
  int j = tid;  // 256 outputs
  const float* wr = hw + (size_t)j*DM;
  float acc = hb[j];
#pragma unroll 4
  for (int k=0;k<DM;k++) acc += mv[k]*wr[k];
  out[(size_t)b*256 + j] = gelu_f(acc);
}

extern "C" void kernel_launch(void* const* d_in, const int* in_sizes, int n_in,
                              void* d_out, int out_size, void* d_ws, size_t ws_size,
                              hipStream_t stream) {
  const float* x       = (const float*)d_in[0];
  const float* pe_w    = (const float*)d_in[1];
  const float* pe_b    = (const float*)d_in[2];
  const float* gn_g    = (const float*)d_in[3];
  const float* gn_b    = (const float*)d_in[4];
  const float* pos     = (const float*)d_in[5];
  const float* ln1_g   = (const float*)d_in[6];
  const float* ln1_b   = (const float*)d_in[7];
  const float* in_w    = (const float*)d_in[8];
  const float* conv_w  = (const float*)d_in[9];
  const float* conv_b  = (const float*)d_in[10];
  const float* xproj_w = (const float*)d_in[11];
  const float* dtproj_w= (const float*)d_in[12];
  const float* dtproj_b= (const float*)d_in[13];
  const float* A_log   = (const float*)d_in[14];
  const float* Dp      = (const float*)d_in[15];
  const float* outw    = (const float*)d_in[16];
  const float* ln2_g   = (const float*)d_in[17];
  const float* ln2_b   = (const float*)d_in[18];
  const float* ffn_w1  = (const float*)d_in[19];
  const float* ffn_b1  = (const float*)d_in[20];
  const float* ffn_w2  = (const float*)d_in[21];
  const float* ffn_b2  = (const float*)d_in[22];
  const float* lnf_g   = (const float*)d_in[23];
  const float* lnf_b   = (const float*)d_in[24];
  const float* head_w  = (const float*)d_in[25];
  const float* head_b  = (const float*)d_in[26];
  float* out = (float*)d_out;

  float* ws  = (float*)d_ws;
  float* h   = ws;                         // TOKS*128
  float* u   = h   + (size_t)TOKS*DM;      // TOKS*128
  float* xz  = u   + (size_t)TOKS*DM;      // TOKS*512 (also stem conv buf, also ffn hidden)
  float* uss = xz  + (size_t)TOKS*512;     // TOKS*256
  float* dlt = uss + (size_t)TOKS*DI;      // TOKS*256 (delta, then y in-place)
  float* Bmw = dlt + (size_t)TOKS*DI;      // TOKS*16
  float* Cmw = Bmw + (size_t)TOKS*DS;      // TOKS*16

  pe_conv_kernel<<<BATCH, 256, 0, stream>>>(x, pe_w, pe_b, xz);
  gn_kernel<<<BATCH*8, 256, 0, stream>>>(xz, gn_g, gn_b, pos, h);

  for (int i = 0; i < NBLK; ++i) {
    ln_kernel<<<TOKS/4, 256, 0, stream>>>(h, ln1_g + i*DM, ln1_b + i*DM, u);
    gemm_kernel<0,0,0><<<dim3(TOKS/64, 8), 256, 0, stream>>>(
        u, in_w + (size_t)i*512*DM, nullptr, xz, 512, DM);
    dwconv_kernel<<<TOKS, 256, 0, stream>>>(xz, conv_w + i*DI*4, conv_b + i*DI, uss);
    xproj_kernel<<<TOKS/64, 256, 0, stream>>>(
        uss, xproj_w + (size_t)i*40*DI, dtproj_w + (size_t)i*DI*DR, dtproj_b + i*DI,
        dlt, Bmw, Cmw);
    scan_kernel<<<BATCH, 256, 0, stream>>>(
        uss, dlt, Bmw, Cmw, A_log + (size_t)i*DI*DS, Dp + i*DI, xz);
    gemm_kernel<0,1,0><<<dim3(TOKS/64, 2), 256, 0, stream>>>(
        dlt, outw + (size_t)i*DM*DI, nullptr, h, DM, DI);
    ln_kernel<<<TOKS/4, 256, 0, stream>>>(h, ln2_g + i*DM, ln2_b + i*DM, u);
    gemm_kernel<1,0,1><<<dim3(TOKS/64, 8), 256, 0, stream>>>(
        u, ffn_w1 + (size_t)i*512*DM, ffn_b1 + i*512, xz, 512, DM);
    gemm_kernel<0,1,1><<<dim3(TOKS/64, 2), 256, 0, stream>>>(
        xz, ffn_w2 + (size_t)i*DM*512, ffn_b2 + i*DM, h, DM, 512);
  }

  final_kernel<<<BATCH, 256, 0, stream>>>(h, lnf_g, lnf_b, head_w, head_b, out);
}

// Round 4
// 1629.371 us; speedup vs baseline: 1.6648x; 1.6648x over previous
//
#include <hip/hip_runtime.h>
#include <math.h>

#define TOKS (128*199)   // 25472
#define DM 128
#define DI 256
#define DS 16
#define DR 8
#define NBLK 4
#define LSEQ 199
#define BATCH 128

typedef __attribute__((ext_vector_type(8))) short bf16x8;
typedef __attribute__((ext_vector_type(4))) float f32x4;

__device__ __forceinline__ float gelu_f(float x) {
  return 0.5f * x * (1.0f + erff(x * 0.70710678118654752440f));
}
__device__ __forceinline__ float silu_f(float x) {
  return x / (1.0f + expf(-x));
}
__device__ __forceinline__ unsigned short f2bf(float f) {   // round-to-nearest-even
  unsigned u = __float_as_uint(f);
  u += 0x7fffu + ((u >> 16) & 1u);
  return (unsigned short)(u >> 16);
}
__device__ __forceinline__ float bf2f(unsigned short h) {
  return __uint_as_float(((unsigned)h) << 16);
}

// ---------------- Stem: conv1d stride 5, kernel 10, 12 leads -> 128 ch ----------------
__global__ void pe_conv_kernel(const float* __restrict__ x, const float* __restrict__ pw,
                               const float* __restrict__ pb, float* __restrict__ convo) {
  int b = blockIdx.x;
  __shared__ float sx[12000];
  for (int i = threadIdx.x; i < 12000; i += 256) sx[i] = x[(size_t)b*12000 + i];
  __syncthreads();
  for (int o = threadIdx.x; o < DM*LSEQ; o += 256) {
    int m = o / LSEQ, t = o - m*LSEQ;
    const float* wr = pw + m*120;
    const float* xt = sx + t*5;
    float acc = pb[m];
#pragma unroll
    for (int l = 0; l < 12; ++l) {
#pragma unroll
      for (int k = 0; k < 10; ++k)
        acc += xt[l*1000 + k] * wr[l*10 + k];
    }
    convo[((size_t)b*DM + m)*LSEQ + t] = acc;
  }
}

// ---------------- GroupNorm(8 groups) + GELU + transpose + pos add ----------------
__global__ void gn_kernel(const float* __restrict__ conv, const float* __restrict__ gg,
                          const float* __restrict__ gb, const float* __restrict__ pos,
                          float* __restrict__ h) {
  int b = blockIdx.x >> 3, grp = blockIdx.x & 7;
  const float* cb = conv + ((size_t)b*DM + grp*16)*LSEQ;
  int tid = threadIdx.x;
  float s = 0.f, s2 = 0.f;
  for (int i = tid; i < 16*LSEQ; i += 256) { float v = cb[i]; s += v; s2 += v*v; }
#pragma unroll
  for (int m = 1; m < 64; m <<= 1) { s += __shfl_xor(s, m); s2 += __shfl_xor(s2, m); }
  __shared__ float red[8];
  int lane = tid & 63, wid = tid >> 6;
  if (lane == 0) { red[wid] = s; red[4+wid] = s2; }
  __syncthreads();
  float S  = red[0]+red[1]+red[2]+red[3];
  float S2 = red[4]+red[5]+red[6]+red[7];
  const float inv = 1.0f/(16.0f*LSEQ);
  float mean = S*inv;
  float var  = S2*inv - mean*mean;
  float rstd = rsqrtf(var + 1e-5f);
  for (int i = tid; i < 16*LSEQ; i += 256) {
    int mloc = i / LSEQ; int t = i - mloc*LSEQ;
    int m = grp*16 + mloc;
    float v = (cb[i] - mean)*rstd*gg[m] + gb[m];
    v = gelu_f(v);
    h[((size_t)b*LSEQ + t)*DM + m] = v + pos[t*DM + m];
  }
}

// ---------------- LayerNorm over DM=128, one wave per token ----------------
__global__ void ln_kernel(const float* __restrict__ x, const float* __restrict__ g,
                          const float* __restrict__ bb, float* __restrict__ o) {
  int tok = blockIdx.x*4 + (threadIdx.x >> 6);
  int lane = threadIdx.x & 63;
  const float* xr = x + (size_t)tok*DM;
  float v0 = xr[lane], v1 = xr[lane+64];
  float s = v0+v1, s2 = v0*v0+v1*v1;
#pragma unroll
  for (int m=1;m<64;m<<=1){ s += __shfl_xor(s,m); s2 += __shfl_xor(s2,m); }
  float mean = s*(1.f/DM);
  float var  = s2*(1.f/DM) - mean*mean;
  float rs = rsqrtf(var+1e-5f);
  float* orow = o + (size_t)tok*DM;
  orow[lane]    = (v0-mean)*rs*g[lane]+bb[lane];
  orow[lane+64] = (v1-mean)*rs*g[lane+64]+bb[lane+64];
}

// ---------------- bf16-split MFMA GEMM: C[M,N] = act(A[M,K] @ W[N,K]^T + bias)(+C) -----
// a = a_hi + a_lo (RNE bf16 split); C ~= ah*wh + al*wh + ah*wl (drop al*wl, ~2^-16 rel).
// Block: 256 thr = 4 waves; tile 64(M) x 64(N); wave w owns rows w*16..w*16+15.
__device__ __forceinline__ void cvt_store(unsigned short* hp, unsigned short* lp,
                                          float4 x0, float4 x1) {
  float v[8] = {x0.x,x0.y,x0.z,x0.w,x1.x,x1.y,x1.z,x1.w};
  unsigned hi[4], lo[4];
#pragma unroll
  for (int j = 0; j < 4; ++j) {
    unsigned short h0 = f2bf(v[2*j]),   h1 = f2bf(v[2*j+1]);
    float r0 = v[2*j]   - bf2f(h0);
    float r1 = v[2*j+1] - bf2f(h1);
    unsigned short l0 = f2bf(r0), l1 = f2bf(r1);
    hi[j] = (unsigned)h0 | ((unsigned)h1 << 16);
    lo[j] = (unsigned)l0 | ((unsigned)l1 << 16);
  }
  *(uint4*)hp = make_uint4(hi[0],hi[1],hi[2],hi[3]);
  *(uint4*)lp = make_uint4(lo[0],lo[1],lo[2],lo[3]);
}

template<int ACT, int RESID, int BIAS, int WGUARD>
__global__ __launch_bounds__(256) void gemm_mfma(
    const float* __restrict__ A, const float* __restrict__ W,
    const float* __restrict__ bias, float* __restrict__ C,
    int N, int K, int Nw) {
  __shared__ unsigned short Ah[64][40], Al[64][40], Wh[64][40], Wl[64][40];
  int tid = threadIdx.x;
  int w = tid >> 6, l = tid & 63;
  int fr = l & 15, fq = l >> 4;
  int r = tid >> 2, seg = tid & 3;                 // staging: row r, 8-elem segment seg
  const float* Ap = A + (size_t)blockIdx.x*64*K + (size_t)r*K + seg*8;
  const float* Wp = W + (size_t)blockIdx.y*64*K + (size_t)r*K + seg*8;
  int wrow = blockIdx.y*64 + r;
  f32x4 acc[4];
#pragma unroll
  for (int ns = 0; ns < 4; ++ns) acc[ns] = (f32x4){0.f,0.f,0.f,0.f};

  for (int k0 = 0; k0 < K; k0 += 32) {
    float4 a0 = *(const float4*)(Ap + k0);
    float4 a1 = *(const float4*)(Ap + k0 + 4);
    float4 w0, w1;
    if (!WGUARD || wrow < Nw) {
      w0 = *(const float4*)(Wp + k0);
      w1 = *(const float4*)(Wp + k0 + 4);
    } else {
      w0 = make_float4(0.f,0.f,0.f,0.f); w1 = w0;
    }
    __syncthreads();                               // prev reads done before overwrite
    cvt_store(&Ah[r][seg*8], &Al[r][seg*8], a0, a1);
    cvt_store(&Wh[r][seg*8], &Wl[r][seg*8], w0, w1);
    __syncthreads();
    bf16x8 ah = *(const bf16x8*)&Ah[w*16 + fr][fq*8];
    bf16x8 al = *(const bf16x8*)&Al[w*16 + fr][fq*8];
#pragma unroll
    for (int ns = 0; ns < 4; ++ns) {
      bf16x8 wh = *(const bf16x8*)&Wh[ns*16 + fr][fq*8];
      bf16x8 wl = *(const bf16x8*)&Wl[ns*16 + fr][fq*8];
      acc[ns] = __builtin_amdgcn_mfma_f32_16x16x32_bf16(ah, wh, acc[ns], 0, 0, 0);
      acc[ns] = __builtin_amdgcn_mfma_f32_16x16x32_bf16(al, wh, acc[ns], 0, 0, 0);
      acc[ns] = __builtin_amdgcn_mfma_f32_16x16x32_bf16(ah, wl, acc[ns], 0, 0, 0);
    }
  }
  int row0 = blockIdx.x*64 + w*16 + fq*4;
#pragma unroll
  for (int ns = 0; ns < 4; ++ns) {
    int col = blockIdx.y*64 + ns*16 + fr;
    if (WGUARD && col >= Nw) continue;
#pragma unroll
    for (int v = 0; v < 4; ++v) {
      float val = acc[ns][v];
      if (BIAS) val += bias[col];
      if (ACT)  val = gelu_f(val);
      float* cp = C + (size_t)(row0+v)*N + col;
      if (RESID) val += *cp;
      *cp = val;
    }
  }
}

// ---------------- Depthwise causal conv (k=4) + bias + SiLU ----------------
__global__ void dwconv_kernel(const float* __restrict__ xz, const float* __restrict__ w,
                              const float* __restrict__ bias, float* __restrict__ uss) {
  int tok = blockIdx.x;
  int d = threadIdx.x;
  int b = tok / LSEQ, t = tok - b*LSEQ;
  float4 wv = *(const float4*)(w + d*4);
  float acc = bias[d];
  const float* xp = xz + ((size_t)b*LSEQ)*512 + d;
  if (t >= 3) acc += xp[(size_t)(t-3)*512]*wv.x;
  if (t >= 2) acc += xp[(size_t)(t-2)*512]*wv.y;
  if (t >= 1) acc += xp[(size_t)(t-1)*512]*wv.z;
  acc += xp[(size_t)t*512]*wv.w;
  uss[(size_t)tok*DI + d] = silu_f(acc);
}

// ---------------- dtproj (8->256) + softplus; reads dbl[tok][0..7] ----------------
__global__ __launch_bounds__(256) void dtproj_kernel(
    const float* __restrict__ dbl, const float* __restrict__ dtw,
    const float* __restrict__ dtb, float* __restrict__ dlt) {
  int tok = blockIdx.x;
  int d = threadIdx.x;
  __shared__ float sdt[8];
  if (d < 8) sdt[d] = dbl[(size_t)tok*40 + d];
  __syncthreads();
  float acc = dtb[d];
#pragma unroll
  for (int rr = 0; rr < DR; ++rr) acc += sdt[rr]*dtw[d*DR + rr];
  acc = (acc > 20.f) ? acc : log1pf(expf(acc));
  dlt[(size_t)tok*DI + d] = acc;
}

// ---------------- Selective scan, state-parallel: thread=(channel,state) ----------------
// Block = 256 thr = 16 channels x 16 states; grid = BATCH*16. y over-writes dlt.
// B/C read directly from dbl ([TOKS][40]: B at +8, C at +24). Gated by silu(z).
__global__ __launch_bounds__(256) void scan_kernel(
    const float* __restrict__ uss, float* __restrict__ dlt_y,
    const float* __restrict__ dbl,
    const float* __restrict__ A_log, const float* __restrict__ Dp,
    const float* __restrict__ xz) {
  int bg = blockIdx.x;
  int b = bg >> 4, dg = bg & 15;
  int tid = threadIdx.x;
  int s = tid & 15, dloc = tid >> 4;
  int d = dg*16 + dloc;
  float As = -expf(A_log[d*DS + s]);
  float Dd = Dp[d];
  float h = 0.f;
  size_t tokbase = (size_t)b*LSEQ;
  const float* pdt = dlt_y + tokbase*DI + d;
  const float* pu  = uss   + tokbase*DI + d;
  const float* pz  = xz    + tokbase*512 + 256 + d;
  const float* pB  = dbl   + tokbase*40 + 8  + s;
  const float* pC  = dbl   + tokbase*40 + 24 + s;
  float* po = dlt_y + tokbase*DI + d;
  float dt_c = *pdt, u_c = *pu, z_c = *pz, B_c = *pB, C_c = *pC;
  for (int t = 0; t < LSEQ; ++t) {
    float dt = dt_c, u = u_c, z = z_c, Bv = B_c, Cv = C_c;
    if (t + 1 < LSEQ) {     // prefetch next step while computing this one
      pdt += DI; pu += DI; pz += 512; pB += 40; pC += 40;
      dt_c = *pdt; u_c = *pu; z_c = *pz; B_c = *pB; C_c = *pC;
    }
    float dA = expf(dt*As);
    h = fmaf(dA, h, dt*u*Bv);
    float p = h*Cv;
    p += __shfl_xor(p, 1);
    p += __shfl_xor(p, 2);
    p += __shfl_xor(p, 4);
    p += __shfl_xor(p, 8);
    float yv = (p + u*Dd) * silu_f(z);
    if (s == 0) *po = yv;
    po += DI;
  }
}

// ---------------- Final: LN + mean over t + head GEMM + GELU ----------------
__global__ void final_kernel(const float* __restrict__ h, const float* __restrict__ g,
                             const float* __restrict__ bta, const float* __restrict__ hw,
                             const float* __restrict__ hb, float* __restrict__ out) {
  int b = blockIdx.x;
  int tid = threadIdx.x, lane = tid & 63, wid = tid >> 6;
  float s0 = 0.f, s1 = 0.f;
  for (int t = wid; t < LSEQ; t += 4) {
    const float* hr = h + ((size_t)b*LSEQ + t)*DM;
    float v0 = hr[lane], v1 = hr[lane+64];
    float ss = v0+v1, ss2 = v0*v0+v1*v1;
#pragma unroll
    for (int m=1;m<64;m<<=1){ ss += __shfl_xor(ss,m); ss2 += __shfl_xor(ss2,m); }
    float mean = ss*(1.f/DM);
    float var  = ss2*(1.f/DM)-mean*mean;
    float rs = rsqrtf(var+1e-5f);
    s0 += (v0-mean)*rs*g[lane]+bta[lane];
    s1 += (v1-mean)*rs*g[lane+64]+bta[lane+64];
  }
  __shared__ float sm[4][128];
  sm[wid][lane] = s0; sm[wid][lane+64] = s1;
  __syncthreads();
  __shared__ float mv[128];
  if (tid < 128) mv[tid] = (sm[0][tid]+sm[1][tid]+sm[2][tid]+sm[3][tid]) * (1.f/199.f);
  __syncthreads();
  int j = tid;  // 256 outputs
  const float* wr = hw + (size_t)j*DM;
  float acc = hb[j];
#pragma unroll 4
  for (int k=0;k<DM;k++) acc += mv[k]*wr[k];
  out[(size_t)b*256 + j] = gelu_f(acc);
}

extern "C" void kernel_launch(void* const* d_in, const int* in_sizes, int n_in,
                              void* d_out, int out_size, void* d_ws, size_t ws_size,
                              hipStream_t stream) {
  const float* x       = (const float*)d_in[0];
  const float* pe_w    = (const float*)d_in[1];
  const float* pe_b    = (const float*)d_in[2];
  const float* gn_g    = (const float*)d_in[3];
  const float* gn_b    = (const float*)d_in[4];
  const float* pos     = (const float*)d_in[5];
  const float* ln1_g   = (const float*)d_in[6];
  const float* ln1_b   = (const float*)d_in[7];
  const float* in_w    = (const float*)d_in[8];
  const float* conv_w  = (const float*)d_in[9];
  const float* conv_b  = (const float*)d_in[10];
  const float* xproj_w = (const float*)d_in[11];
  const float* dtproj_w= (const float*)d_in[12];
  const float* dtproj_b= (const float*)d_in[13];
  const float* A_log   = (const float*)d_in[14];
  const float* Dp      = (const float*)d_in[15];
  const float* outw    = (const float*)d_in[16];
  const float* ln2_g   = (const float*)d_in[17];
  const float* ln2_b   = (const float*)d_in[18];
  const float* ffn_w1  = (const float*)d_in[19];
  const float* ffn_b1  = (const float*)d_in[20];
  const float* ffn_w2  = (const float*)d_in[21];
  const float* ffn_b2  = (const float*)d_in[22];
  const float* lnf_g   = (const float*)d_in[23];
  const float* lnf_b   = (const float*)d_in[24];
  const float* head_w  = (const float*)d_in[25];
  const float* head_b  = (const float*)d_in[26];
  float* out = (float*)d_out;

  float* ws  = (float*)d_ws;
  float* h   = ws;                         // TOKS*128
  float* u   = h   + (size_t)TOKS*DM;      // TOKS*128
  float* xz  = u   + (size_t)TOKS*DM;      // TOKS*512 (stem buf / in_proj out / ffn hidden)
  float* uss = xz  + (size_t)TOKS*512;     // TOKS*256
  float* dlt = uss + (size_t)TOKS*DI;      // TOKS*256 (delta, then y in-place)
  float* dbl = dlt + (size_t)TOKS*DI;      // TOKS*40  (xproj out: dt|B|C)

  pe_conv_kernel<<<BATCH, 256, 0, stream>>>(x, pe_w, pe_b, xz);
  gn_kernel<<<BATCH*8, 256, 0, stream>>>(xz, gn_g, gn_b, pos, h);

  for (int i = 0; i < NBLK; ++i) {
    ln_kernel<<<TOKS/4, 256, 0, stream>>>(h, ln1_g + i*DM, ln1_b + i*DM, u);
    gemm_mfma<0,0,0,0><<<dim3(TOKS/64, 8), 256, 0, stream>>>(
        u, in_w + (size_t)i*512*DM, nullptr, xz, 512, DM, 0);
    dwconv_kernel<<<TOKS, 256, 0, stream>>>(xz, conv_w + i*DI*4, conv_b + i*DI, uss);
    gemm_mfma<0,0,0,1><<<dim3(TOKS/64, 1), 256, 0, stream>>>(
        uss, xproj_w + (size_t)i*40*DI, nullptr, dbl, 40, DI, 40);
    dtproj_kernel<<<TOKS, 256, 0, stream>>>(
        dbl, dtproj_w + (size_t)i*DI*DR, dtproj_b + i*DI, dlt);
    scan_kernel<<<BATCH*16, 256, 0, stream>>>(
        uss, dlt, dbl, A_log + (size_t)i*DI*DS, Dp + i*DI, xz);
    gemm_mfma<0,1,0,0><<<dim3(TOKS/64, 2), 256, 0, stream>>>(
        dlt, outw + (size_t)i*DM*DI, nullptr, h, DM, DI, 0);
    ln_kernel<<<TOKS/4, 256, 0, stream>>>(h, ln2_g + i*DM, ln2_b + i*DM, u);
    gemm_mfma<1,0,1,0><<<dim3(TOKS/64, 8), 256, 0, stream>>>(
        u, ffn_w1 + (size_t)i*512*DM, ffn_b1 + i*512, xz, 512, DM, 0);
    gemm_mfma<0,1,1,0><<<dim3(TOKS/64, 2), 256, 0, stream>>>(
        xz, ffn_w2 + (size_t)i*DM*512, ffn_b2 + i*DM, h, DM, 512, 0);
  }

  final_kernel<<<BATCH, 256, 0, stream>>>(h, lnf_g, lnf_b, head_w, head_b, out);
}

// Round 6
// 1352.784 us; speedup vs baseline: 2.0051x; 1.2045x over previous
//
#include <hip/hip_runtime.h>
#include <math.h>

#define TOKS (128*199)   // 25472
#define DM 128
#define DI 256
#define DS 16
#define DR 8
#define NBLK 4
#define LSEQ 199
#define BATCH 128

typedef __attribute__((ext_vector_type(8))) short bf16x8;
typedef __attribute__((ext_vector_type(4))) float f32x4;

__device__ __forceinline__ float gelu_f(float x) {
  return 0.5f * x * (1.0f + erff(x * 0.70710678118654752440f));
}
__device__ __forceinline__ float silu_fast(float x) {
  float e = __expf(-x);
  return x * __builtin_amdgcn_rcpf(1.0f + e);
}
__device__ __forceinline__ unsigned short f2bf(float f) {   // round-to-nearest-even
  unsigned u = __float_as_uint(f);
  u += 0x7fffu + ((u >> 16) & 1u);
  return (unsigned short)(u >> 16);
}
__device__ __forceinline__ float bf2f(unsigned short h) {
  return __uint_as_float(((unsigned)h) << 16);
}

// ---------------- Stem: conv1d stride 5, kernel 10, 12 leads -> 128 ch ----------------
// Tiled over t: grid (BATCH, 8), each block does 25 (24 last) output positions.
__global__ __launch_bounds__(256) void pe_conv_kernel(
    const float* __restrict__ x, const float* __restrict__ pw,
    const float* __restrict__ pb, float* __restrict__ convo) {
  int b = blockIdx.x, tc = blockIdx.y;
  int t0 = tc * 25;
  int nt = (LSEQ - t0 < 25) ? (LSEQ - t0) : 25;
  __shared__ float sx[12][136];
  int tid = threadIdx.x;
  for (int i = tid; i < 12*136; i += 256) {
    int l = i / 136, k = i - l*136;
    int idx = t0*5 + k;
    sx[l][k] = (idx < 1000) ? x[(size_t)b*12000 + l*1000 + idx] : 0.f;
  }
  __syncthreads();
  for (int o = tid; o < DM*nt; o += 256) {
    int m = o / nt, tt = o - m*nt;
    const float* wr = pw + m*120;
    float acc = pb[m];
#pragma unroll
    for (int l = 0; l < 12; ++l) {
#pragma unroll
      for (int k = 0; k < 10; ++k)
        acc += sx[l][tt*5 + k] * wr[l*10 + k];
    }
    convo[((size_t)b*DM + m)*LSEQ + t0 + tt] = acc;
  }
}

// ---------------- GroupNorm(8 groups) + GELU + transpose + pos add ----------------
__global__ void gn_kernel(const float* __restrict__ conv, const float* __restrict__ gg,
                          const float* __restrict__ gb, const float* __restrict__ pos,
                          float* __restrict__ h) {
  int b = blockIdx.x >> 3, grp = blockIdx.x & 7;
  const float* cb = conv + ((size_t)b*DM + grp*16)*LSEQ;
  int tid = threadIdx.x;
  float s = 0.f, s2 = 0.f;
  for (int i = tid; i < 16*LSEQ; i += 256) { float v = cb[i]; s += v; s2 += v*v; }
#pragma unroll
  for (int m = 1; m < 64; m <<= 1) { s += __shfl_xor(s, m); s2 += __shfl_xor(s2, m); }
  __shared__ float red[8];
  int lane = tid & 63, wid = tid >> 6;
  if (lane == 0) { red[wid] = s; red[4+wid] = s2; }
  __syncthreads();
  float S  = red[0]+red[1]+red[2]+red[3];
  float S2 = red[4]+red[5]+red[6]+red[7];
  const float inv = 1.0f/(16.0f*LSEQ);
  float mean = S*inv;
  float var  = S2*inv - mean*mean;
  float rstd = rsqrtf(var + 1e-5f);
  for (int i = tid; i < 16*LSEQ; i += 256) {
    int mloc = i / LSEQ; int t = i - mloc*LSEQ;
    int m = grp*16 + mloc;
    float v = (cb[i] - mean)*rstd*gg[m] + gb[m];
    v = gelu_f(v);
    h[((size_t)b*LSEQ + t)*DM + m] = v + pos[t*DM + m];
  }
}

// ---------------- LayerNorm over DM=128, one wave per token ----------------
__global__ void ln_kernel(const float* __restrict__ x, const float* __restrict__ g,
                          const float* __restrict__ bb, float* __restrict__ o) {
  int tok = blockIdx.x*4 + (threadIdx.x >> 6);
  int lane = threadIdx.x & 63;
  const float* xr = x + (size_t)tok*DM;
  float v0 = xr[lane], v1 = xr[lane+64];
  float s = v0+v1, s2 = v0*v0+v1*v1;
#pragma unroll
  for (int m=1;m<64;m<<=1){ s += __shfl_xor(s,m); s2 += __shfl_xor(s2,m); }
  float mean = s*(1.f/DM);
  float var  = s2*(1.f/DM) - mean*mean;
  float rs = rsqrtf(var+1e-5f);
  float* orow = o + (size_t)tok*DM;
  orow[lane]    = (v0-mean)*rs*g[lane]+bb[lane];
  orow[lane+64] = (v1-mean)*rs*g[lane+64]+bb[lane+64];
}

// ---------------- bf16-split MFMA GEMM: C[M,N] = act(A[M,K] @ W[N,K]^T + bias)(+C) -----
__device__ __forceinline__ void cvt_store(unsigned short* hp, unsigned short* lp,
                                          float4 x0, float4 x1) {
  float v[8] = {x0.x,x0.y,x0.z,x0.w,x1.x,x1.y,x1.z,x1.w};
  unsigned hi[4], lo[4];
#pragma unroll
  for (int j = 0; j < 4; ++j) {
    unsigned short h0 = f2bf(v[2*j]),   h1 = f2bf(v[2*j+1]);
    float r0 = v[2*j]   - bf2f(h0);
    float r1 = v[2*j+1] - bf2f(h1);
    unsigned short l0 = f2bf(r0), l1 = f2bf(r1);
    hi[j] = (unsigned)h0 | ((unsigned)h1 << 16);
    lo[j] = (unsigned)l0 | ((unsigned)l1 << 16);
  }
  *(uint4*)hp = make_uint4(hi[0],hi[1],hi[2],hi[3]);
  *(uint4*)lp = make_uint4(lo[0],lo[1],lo[2],lo[3]);
}

template<int ACT, int RESID, int BIAS, int WGUARD>
__global__ __launch_bounds__(256) void gemm_mfma(
    const float* __restrict__ A, const float* __restrict__ W,
    const float* __restrict__ bias, float* __restrict__ C,
    int N, int K, int Nw) {
  __shared__ unsigned short Ah[64][40], Al[64][40], Wh[64][40], Wl[64][40];
  int tid = threadIdx.x;
  int w = tid >> 6, l = tid & 63;
  int fr = l & 15, fq = l >> 4;
  int r = tid >> 2, seg = tid & 3;                 // staging: row r, 8-elem segment seg
  const float* Ap = A + (size_t)blockIdx.x*64*K + (size_t)r*K + seg*8;
  const float* Wp = W + (size_t)blockIdx.y*64*K + (size_t)r*K + seg*8;
  int wrow = blockIdx.y*64 + r;
  f32x4 acc[4];
#pragma unroll
  for (int ns = 0; ns < 4; ++ns) acc[ns] = (f32x4){0.f,0.f,0.f,0.f};

  for (int k0 = 0; k0 < K; k0 += 32) {
    float4 a0 = *(const float4*)(Ap + k0);
    float4 a1 = *(const float4*)(Ap + k0 + 4);
    float4 w0, w1;
    if (!WGUARD || wrow < Nw) {
      w0 = *(const float4*)(Wp + k0);
      w1 = *(const float4*)(Wp + k0 + 4);
    } else {
      w0 = make_float4(0.f,0.f,0.f,0.f); w1 = w0;
    }
    __syncthreads();                               // prev reads done before overwrite
    cvt_store(&Ah[r][seg*8], &Al[r][seg*8], a0, a1);
    cvt_store(&Wh[r][seg*8], &Wl[r][seg*8], w0, w1);
    __syncthreads();
    bf16x8 ah = *(const bf16x8*)&Ah[w*16 + fr][fq*8];
    bf16x8 al = *(const bf16x8*)&Al[w*16 + fr][fq*8];
#pragma unroll
    for (int ns = 0; ns < 4; ++ns) {
      bf16x8 wh = *(const bf16x8*)&Wh[ns*16 + fr][fq*8];
      bf16x8 wl = *(const bf16x8*)&Wl[ns*16 + fr][fq*8];
      acc[ns] = __builtin_amdgcn_mfma_f32_16x16x32_bf16(ah, wh, acc[ns], 0, 0, 0);
      acc[ns] = __builtin_amdgcn_mfma_f32_16x16x32_bf16(al, wh, acc[ns], 0, 0, 0);
      acc[ns] = __builtin_amdgcn_mfma_f32_16x16x32_bf16(ah, wl, acc[ns], 0, 0, 0);
    }
  }
  int row0 = blockIdx.x*64 + w*16 + fq*4;
#pragma unroll
  for (int ns = 0; ns < 4; ++ns) {
    int col = blockIdx.y*64 + ns*16 + fr;
    if (WGUARD && col >= Nw) continue;
#pragma unroll
    for (int v = 0; v < 4; ++v) {
      float val = acc[ns][v];
      if (BIAS) val += bias[col];
      if (ACT)  val = gelu_f(val);
      float* cp = C + (size_t)(row0+v)*N + col;
      if (RESID) val += *cp;
      *cp = val;
    }
  }
}

// ---------------- Depthwise causal conv (k=4) + bias + SiLU ----------------
__global__ void dwconv_kernel(const float* __restrict__ xz, const float* __restrict__ w,
                              const float* __restrict__ bias, float* __restrict__ uss) {
  int tok = blockIdx.x;
  int d = threadIdx.x;
  int b = tok / LSEQ, t = tok - b*LSEQ;
  float4 wv = *(const float4*)(w + d*4);
  float acc = bias[d];
  const float* xp = xz + ((size_t)b*LSEQ)*512 + d;
  if (t >= 3) acc += xp[(size_t)(t-3)*512]*wv.x;
  if (t >= 2) acc += xp[(size_t)(t-2)*512]*wv.y;
  if (t >= 1) acc += xp[(size_t)(t-1)*512]*wv.z;
  acc += xp[(size_t)t*512]*wv.w;
  uss[(size_t)tok*DI + d] = silu_fast(acc);
}

// ---------------- dtproj (8->256) + softplus; 8 tokens per block ----------------
__global__ __launch_bounds__(256) void dtproj_kernel(
    const float* __restrict__ dbl, const float* __restrict__ dtw,
    const float* __restrict__ dtb, float* __restrict__ dlt) {
  int tok0 = blockIdx.x * 8;
  int d = threadIdx.x;
  __shared__ float sdt[8][DR];
  if (d < 64) sdt[d >> 3][d & 7] = dbl[(size_t)(tok0 + (d >> 3))*40 + (d & 7)];
  float wreg[DR];
#pragma unroll
  for (int rr = 0; rr < DR; ++rr) wreg[rr] = dtw[d*DR + rr];
  float b0 = dtb[d];
  __syncthreads();
#pragma unroll
  for (int tt = 0; tt < 8; ++tt) {
    float acc = b0;
#pragma unroll
    for (int rr = 0; rr < DR; ++rr) acc += sdt[tt][rr]*wreg[rr];
    acc = (acc > 20.f) ? acc : log1pf(__expf(acc));
    dlt[(size_t)(tok0 + tt)*DI + d] = acc;
  }
}

// ---------------- Selective scan, state-parallel: thread=(channel,state) ----------------
// Block = 256 thr = 16 channels x 16 states; grid = BATCH*16. y over-writes dlt.
__global__ __launch_bounds__(256) void scan_kernel(
    const float* __restrict__ uss, float* __restrict__ dlt_y,
    const float* __restrict__ dbl,
    const float* __restrict__ A_log, const float* __restrict__ Dp,
    const float* __restrict__ xz) {
  int bg = blockIdx.x;
  int b = bg >> 4, dg = bg & 15;
  int tid = threadIdx.x;
  int s = tid & 15, dloc = tid >> 4;
  int d = dg*16 + dloc;
  float As = -__expf(A_log[d*DS + s]);
  float Dd = Dp[d];
  float h = 0.f;
  size_t tokbase = (size_t)b*LSEQ;
  const float* pdt = dlt_y + tokbase*DI + d;
  const float* pu  = uss   + tokbase*DI + d;
  const float* pz  = xz    + tokbase*512 + 256 + d;
  const float* pB  = dbl   + tokbase*40 + 8  + s;
  const float* pC  = dbl   + tokbase*40 + 24 + s;
  float* po = dlt_y + tokbase*DI + d;
  float dt_c = *pdt, u_c = *pu, z_c = *pz, B_c = *pB, C_c = *pC;
  for (int t = 0; t < LSEQ; ++t) {
    float dt = dt_c, u = u_c, z = z_c, Bv = B_c, Cv = C_c;
    if (t + 1 < LSEQ) {     // prefetch next step while computing this one
      pdt += DI; pu += DI; pz += 512; pB += 40; pC += 40;
      dt_c = *pdt; u_c = *pu; z_c = *pz; B_c = *pB; C_c = *pC;
    }
    float dA = __expf(dt*As);
    h = fmaf(dA, h, dt*u*Bv);
    float p = h*Cv;
    p += __shfl_xor(p, 1);
    p += __shfl_xor(p, 2);
    p += __shfl_xor(p, 4);
    p += __shfl_xor(p, 8);
    float yv = fmaf(u, Dd, p) * silu_fast(z);
    if (s == 0) *po = yv;
    po += DI;
  }
}

// ---------------- Final: LN + mean over t + head GEMM + GELU ----------------
__global__ void final_kernel(const float* __restrict__ h, const float* __restrict__ g,
                             const float* __restrict__ bta, const float* __restrict__ hw,
                             const float* __restrict__ hb, float* __restrict__ out) {
  int b = blockIdx.x;
  int tid = threadIdx.x, lane = tid & 63, wid = tid >> 6;
  float s0 = 0.f, s1 = 0.f;
  for (int t = wid; t < LSEQ; t += 4) {
    const float* hr = h + ((size_t)b*LSEQ + t)*DM;
    float v0 = hr[lane], v1 = hr[lane+64];
    float ss = v0+v1, ss2 = v0*v0+v1*v1;
#pragma unroll
    for (int m=1;m<64;m<<=1){ ss += __shfl_xor(ss,m); ss2 += __shfl_xor(ss2,m); }
    float mean = ss*(1.f/DM);
    float var  = ss2*(1.f/DM)-mean*mean;
    float rs = rsqrtf(var+1e-5f);
    s0 += (v0-mean)*rs*g[lane]+bta[lane];
    s1 += (v1-mean)*rs*g[lane+64]+bta[lane+64];
  }
  __shared__ float sm[4][128];
  sm[wid][lane] = s0; sm[wid][lane+64] = s1;
  __syncthreads();
  __shared__ float mv[128];
  if (tid < 128) mv[tid] = (sm[0][tid]+sm[1][tid]+sm[2][tid]+sm[3][tid]) * (1.f/199.f);
  __syncthreads();
  int j = tid;  // 256 outputs
  const float* wr = hw + (size_t)j*DM;
  float acc = hb[j];
#pragma unroll 4
  for (int k=0;k<DM;k++) acc += mv[k]*wr[k];
  out[(size_t)b*256 + j] = gelu_f(acc);
}

extern "C" void kernel_launch(void* const* d_in, const int* in_sizes, int n_in,
                              void* d_out, int out_size, void* d_ws, size_t ws_size,
                              hipStream_t stream) {
  const float* x       = (const float*)d_in[0];
  const float* pe_w    = (const float*)d_in[1];
  const float* pe_b    = (const float*)d_in[2];
  const float* gn_g    = (const float*)d_in[3];
  const float* gn_b    = (const float*)d_in[4];
  const float* pos     = (const float*)d_in[5];
  const float* ln1_g   = (const float*)d_in[6];
  const float* ln1_b   = (const float*)d_in[7];
  const float* in_w    = (const float*)d_in[8];
  const float* conv_w  = (const float*)d_in[9];
  const float* conv_b  = (const float*)d_in[10];
  const float* xproj_w = (const float*)d_in[11];
  const float* dtproj_w= (const float*)d_in[12];
  const float* dtproj_b= (const float*)d_in[13];
  const float* A_log   = (const float*)d_in[14];
  const float* Dp      = (const float*)d_in[15];
  const float* outw    = (const float*)d_in[16];
  const float* ln2_g   = (const float*)d_in[17];
  const float* ln2_b   = (const float*)d_in[18];
  const float* ffn_w1  = (const float*)d_in[19];
  const float* ffn_b1  = (const float*)d_in[20];
  const float* ffn_w2  = (const float*)d_in[21];
  const float* ffn_b2  = (const float*)d_in[22];
  const float* lnf_g   = (const float*)d_in[23];
  const float* lnf_b   = (const float*)d_in[24];
  const float* head_w  = (const float*)d_in[25];
  const float* head_b  = (const float*)d_in[26];
  float* out = (float*)d_out;

  float* ws  = (float*)d_ws;
  float* h   = ws;                         // TOKS*128
  float* u   = h   + (size_t)TOKS*DM;      // TOKS*128
  float* xz  = u   + (size_t)TOKS*DM;      // TOKS*512 (stem buf / in_proj out / ffn hidden)
  float* uss = xz  + (size_t)TOKS*512;     // TOKS*256
  float* dlt = uss + (size_t)TOKS*DI;      // TOKS*256 (delta, then y in-place)
  float* dbl = dlt + (size_t)TOKS*DI;      // TOKS*40  (xproj out: dt|B|C)

  pe_conv_kernel<<<dim3(BATCH, 8), 256, 0, stream>>>(x, pe_w, pe_b, xz);
  gn_kernel<<<BATCH*8, 256, 0, stream>>>(xz, gn_g, gn_b, pos, h);

  for (int i = 0; i < NBLK; ++i) {
    ln_kernel<<<TOKS/4, 256, 0, stream>>>(h, ln1_g + i*DM, ln1_b + i*DM, u);
    gemm_mfma<0,0,0,0><<<dim3(TOKS/64, 8), 256, 0, stream>>>(
        u, in_w + (size_t)i*512*DM, nullptr, xz, 512, DM, 0);
    dwconv_kernel<<<TOKS, 256, 0, stream>>>(xz, conv_w + i*DI*4, conv_b + i*DI, uss);
    gemm_mfma<0,0,0,1><<<dim3(TOKS/64, 1), 256, 0, stream>>>(
        uss, xproj_w + (size_t)i*40*DI, nullptr, dbl, 40, DI, 40);
    dtproj_kernel<<<TOKS/8, 256, 0, stream>>>(
        dbl, dtproj_w + (size_t)i*DI*DR, dtproj_b + i*DI, dlt);
    scan_kernel<<<BATCH*16, 256, 0, stream>>>(
        uss, dlt, dbl, A_log + (size_t)i*DI*DS, Dp + i*DI, xz);
    gemm_mfma<0,1,0,0><<<dim3(TOKS/64, 2), 256, 0, stream>>>(
        dlt, outw + (size_t)i*DM*DI, nullptr, h, DM, DI, 0);
    ln_kernel<<<TOKS/4, 256, 0, stream>>>(h, ln2_g + i*DM, ln2_b + i*DM, u);
    gemm_mfma<1,0,1,0><<<dim3(TOKS/64, 8), 256, 0, stream>>>(
        u, ffn_w1 + (size_t)i*512*DM, ffn_b1 + i*512, xz, 512, DM, 0);
    gemm_mfma<0,1,1,0><<<dim3(TOKS/64, 2), 256, 0, stream>>>(
        xz, ffn_w2 + (size_t)i*DM*512, ffn_b2 + i*DM, h, DM, 512, 0);
  }

  final_kernel<<<BATCH, 256, 0, stream>>>(h, lnf_g, lnf_b, head_w, head_b, out);
}